// Round 5
// baseline (666.325 us; speedup 1.0000x reference)
//
#include <hip/hip_runtime.h>

// B=8, N=2048, D_IN=D_OUT=512. out fp32 [8,2048,512].
// ws layout (bytes): xb@0 (16M), Qb@16M, Kb@32M, Vt@48M, Wt@64M(+1.5M).

typedef __bf16 bf16x8 __attribute__((ext_vector_type(8)));
typedef float f32x4 __attribute__((ext_vector_type(4)));

#define AS1G __attribute__((address_space(1)))
#define AS3L __attribute__((address_space(3)))

__device__ __forceinline__ void gload16(const void* g, void* l) {
  __builtin_amdgcn_global_load_lds((const AS1G void*)g, (AS3L void*)l, 16, 0, 0);
}

// ---------------- x fp32 -> bf16 ----------------
__global__ __launch_bounds__(256) void k_xconv(const float* __restrict__ x, __bf16* __restrict__ xb) {
  size_t i = ((size_t)blockIdx.x * 256 + threadIdx.x) * 8;
  const float4* p = (const float4*)(x + i);
  float4 a = p[0], b = p[1];
  bf16x8 v;
  v[0] = (__bf16)a.x; v[1] = (__bf16)a.y; v[2] = (__bf16)a.z; v[3] = (__bf16)a.w;
  v[4] = (__bf16)b.x; v[5] = (__bf16)b.y; v[6] = (__bf16)b.z; v[7] = (__bf16)b.w;
  *(bf16x8*)(xb + i) = v;
}

// ---------------- W [d][e] fp32 -> Wt [z][e][d] bf16 ----------------
__global__ __launch_bounds__(256) void k_wt(const float* __restrict__ Wq, const float* __restrict__ Wk,
                                            const float* __restrict__ Wv, __bf16* __restrict__ Wt) {
  __shared__ float t[32][33];
  int z = blockIdx.z;
  const float* W = (z == 0) ? Wq : (z == 1 ? Wk : Wv);
  int r0 = blockIdx.y * 32, c0 = blockIdx.x * 32;
  int tr = threadIdx.x >> 5, tc = threadIdx.x & 31;
#pragma unroll
  for (int p = 0; p < 4; p++)
    t[tr + p * 8][tc] = W[(size_t)(r0 + tr + p * 8) * 512 + c0 + tc];
  __syncthreads();
#pragma unroll
  for (int p = 0; p < 4; p++)
    Wt[(size_t)z * 262144 + (size_t)(c0 + tr + p * 8) * 512 + r0 + tc] = (__bf16)t[tc][tr + p * 8];
}

// ---------------- fused QKV GEMM: C = xb * Wz^T + bias ----------------
// 128x128 tile, BK=64, 4 waves (2x2 of 64x64), 16x16x32 bf16 MFMA.
// z==0 -> Qb (pre-scaled for exp2 softmax), z==1 -> Kb, z==2 -> Vt (TRANSPOSED store).
__global__ __launch_bounds__(256) void k_gemm(const __bf16* __restrict__ xb, const __bf16* __restrict__ Wt,
                                              const float* __restrict__ bq, const float* __restrict__ bk,
                                              const float* __restrict__ bv,
                                              __bf16* __restrict__ Qb, __bf16* __restrict__ Kb,
                                              __bf16* __restrict__ Vt) {
  __shared__ __bf16 sA[128 * 64];
  __shared__ __bf16 sB[128 * 64];
  int z = blockIdx.y;
  int bx = blockIdx.x;
  int m0 = (bx >> 2) * 128, e0 = (bx & 3) * 128;
  int tid = threadIdx.x, w = tid >> 6, l = tid & 63;
  int lr = l & 15, lg = l >> 4;
  int wm = (w & 1) * 64, wn = (w >> 1) * 64;
  const float* bias = (z == 0) ? bq : (z == 1 ? bk : bv);
  const __bf16* Wz = Wt + (size_t)z * 262144;

  float bval[4];
#pragma unroll
  for (int fn = 0; fn < 4; fn++) bval[fn] = bias[e0 + wn + fn * 16 + lr];

  f32x4 zero4 = {0.f, 0.f, 0.f, 0.f};
  f32x4 acc[4][4];
#pragma unroll
  for (int fm = 0; fm < 4; fm++)
#pragma unroll
    for (int fn = 0; fn < 4; fn++) acc[fm][fn] = zero4;

#pragma unroll 1
  for (int kt = 0; kt < 8; kt++) {
#pragma unroll
    for (int ii = 0; ii < 4; ii++) {
      int rt = (w * 4 + ii) * 8 + (l >> 3);
      int sw = ((l & 7) ^ (l >> 3)) << 3;
      gload16(xb + (size_t)(m0 + rt) * 512 + kt * 64 + sw, sA + (w * 4 + ii) * 512);
      gload16(Wz + (size_t)(e0 + rt) * 512 + kt * 64 + sw, sB + (w * 4 + ii) * 512);
    }
    __syncthreads();
#pragma unroll
    for (int kc = 0; kc < 2; kc++) {
      bf16x8 af[4], bfr[4];
#pragma unroll
      for (int f = 0; f < 4; f++) {
        int ra = wm + f * 16 + lr;
        af[f] = *(const bf16x8*)(sA + ra * 64 + (((kc * 4 + lg) ^ (ra & 7)) << 3));
        int rb = wn + f * 16 + lr;
        bfr[f] = *(const bf16x8*)(sB + rb * 64 + (((kc * 4 + lg) ^ (rb & 7)) << 3));
      }
#pragma unroll
      for (int fm = 0; fm < 4; fm++)
#pragma unroll
        for (int fn = 0; fn < 4; fn++)
          acc[fm][fn] = __builtin_amdgcn_mfma_f32_16x16x32_bf16(af[fm], bfr[fn], acc[fm][fn], 0, 0, 0);
    }
    __syncthreads();
  }

  if (z == 2) {
    // V transposed: Vt[b][e][n], b = row>>11, n = row&2047. 4 consecutive n per lane -> 8B store.
    int bb = m0 >> 11;
#pragma unroll
    for (int fm = 0; fm < 4; fm++) {
      int nl = (m0 & 2047) + wm + fm * 16 + lg * 4;
#pragma unroll
      for (int fn = 0; fn < 4; fn++) {
        alignas(8) __bf16 tmp[4];
#pragma unroll
        for (int r = 0; r < 4; r++) tmp[r] = (__bf16)(acc[fm][fn][r] + bval[fn]);
        *(float2*)(Vt + (size_t)bb * 1048576 + (size_t)(e0 + wn + fn * 16 + lr) * 2048 + nl) =
            *(float2*)tmp;
      }
    }
  } else {
    __bf16* dst = (z == 0) ? Qb : Kb;
    const float qmul = (z == 0) ? (1.4426950408889634f * 0.044194173824159216f) : 1.0f;
#pragma unroll
    for (int fm = 0; fm < 4; fm++)
#pragma unroll
      for (int fn = 0; fn < 4; fn++)
#pragma unroll
        for (int r = 0; r < 4; r++) {
          float v = (acc[fm][fn][r] + bval[fn]) * qmul;
          dst[(size_t)(m0 + wm + fm * 16 + lg * 4 + r) * 512 + e0 + wn + fn * 16 + lr] = (__bf16)v;
        }
  }
}

// ---------------- flash attention: K-from-global, V via double-buffered LDS ----------
// grid 512: b = blk&7 (XCD pin: K/V of batch b stay in XCD b's L2), qt, dh = D-half.
// 256 threads = 4 waves x 16 q-rows. KVBLK=32.
// QK^T reads K DIRECTLY from global (L2-resident, L1-shared across co-resident
// blocks walking the same KV tiles) -> no sK, no K-stage barrier, LDS ops/wave/iter
// drop 69 -> 29 (round-4 counters showed the LDS port ~88% busy = the bottleneck).
// One barrier per iter; V(it+1) staged right after it (full iter to land).
// NOTE: 512-thread blocks pin VGPR to 128 -> spills (rounds 2-3). 256 threads OK.
__global__ __launch_bounds__(256, 2) void k_fa(const __bf16* __restrict__ Qb, const __bf16* __restrict__ Kb,
                                               const __bf16* __restrict__ Vt, float* __restrict__ out) {
  __shared__ __bf16 sV[2][128 * 64];  // paired d-rows: rr = (d-d0)>>1, XOR-swizzled chunks
  __shared__ __bf16 sPall[4 * 640];   // per-wave [16][40]

  int tid = threadIdx.x;
  int w = tid >> 6, l = tid & 63;
  int lr = l & 15, lg = l >> 4;
  __bf16* sP = sPall + w * 640;

  int blk = blockIdx.x;
  int b = blk & 7;
  int q0 = ((blk >> 3) & 31) * 64;
  int d0 = (blk >> 8) * 256;

  const __bf16* Kbase = Kb + (size_t)b * 2048 * 512;
  const __bf16* Vbase = Vt + (size_t)b * 512 * 2048 + (size_t)d0 * 2048;

  // lane-fixed K fragment pointer: kv-row lr (+16 for j=1), k-chunk lg*8 (+32 per dk)
  const __bf16* kl = Kbase + (size_t)lr * 512 + lg * 8;

  // Q A-fragments in registers, full 512 dims (already scaled by log2e/sqrt(512)).
  bf16x8 qf[16];
  const __bf16* qrow = Qb + (size_t)(b * 2048 + q0 + w * 16 + lr) * 512;
#pragma unroll
  for (int dk = 0; dk < 16; dk++) qf[dk] = *(const bf16x8*)(qrow + dk * 32 + lg * 8);

  f32x4 zero4 = {0.f, 0.f, 0.f, 0.f};
  f32x4 o[16];
#pragma unroll
  for (int dj = 0; dj < 16; dj++) o[dj] = zero4;
  float m_run[4] = {-1e30f, -1e30f, -1e30f, -1e30f};
  float l_run[4] = {0.f, 0.f, 0.f, 0.f};

  // prologue: stage V(0) into sV[0]
#pragma unroll
  for (int i = 0; i < 4; i++) {
    int rr = (w * 4 + i) * 8 + (l >> 3);
    int cl = (l & 7) ^ (l >> 3);
    gload16(Vbase + (size_t)(2 * rr + (cl >> 2)) * 2048 + ((cl & 3) << 3), sV[0] + (w * 4 + i) * 512);
  }

#pragma unroll 1
  for (int it = 0; it < 64; it++) {
    int cur = it & 1;
    __syncthreads();  // V(it) landed (staged a full iter ago); PV(it-1) sV reads done

    // stage V(it+1) into the other buffer — lands by the next barrier
    if (it < 63) {
#pragma unroll
      for (int i = 0; i < 4; i++) {
        int rr = (w * 4 + i) * 8 + (l >> 3);
        int cl = (l & 7) ^ (l >> 3);
        gload16(Vbase + (size_t)(2 * rr + (cl >> 2)) * 2048 + (it + 1) * 32 + ((cl & 3) << 3),
                sV[cur ^ 1] + (w * 4 + i) * 512);
      }
    }

    // S = Q K^T, K straight from global (L2). dk chunked x4: 8 loads in flight.
    const __bf16* kt = kl + (size_t)it * 32 * 512;
    f32x4 s[2] = {zero4, zero4};
#pragma unroll
    for (int dq = 0; dq < 4; dq++) {
      bf16x8 ka[4], kc[4];
#pragma unroll
      for (int u = 0; u < 4; u++) {
        ka[u] = *(const bf16x8*)(kt + (dq * 4 + u) * 32);
        kc[u] = *(const bf16x8*)(kt + 16 * 512 + (dq * 4 + u) * 32);
      }
#pragma unroll
      for (int u = 0; u < 4; u++) {
        s[0] = __builtin_amdgcn_mfma_f32_16x16x32_bf16(qf[dq * 4 + u], ka[u], s[0], 0, 0, 0);
        s[1] = __builtin_amdgcn_mfma_f32_16x16x32_bf16(qf[dq * 4 + u], kc[u], s[1], 0, 0, 0);
      }
    }

    // online softmax with defer-rescale (THR=10 in log2 domain)
    float mtv[4];
#pragma unroll
    for (int r = 0; r < 4; r++) {
      float mt = fmaxf(s[0][r], s[1][r]);
#pragma unroll
      for (int msk = 1; msk <= 8; msk <<= 1) mt = fmaxf(mt, __shfl_xor(mt, msk));
      mtv[r] = mt;
    }
    float g4 = fmaxf(fmaxf(mtv[0] - m_run[0], mtv[1] - m_run[1]),
                     fmaxf(mtv[2] - m_run[2], mtv[3] - m_run[3]));
    if (__any(g4 > 10.0f)) {
#pragma unroll
      for (int r = 0; r < 4; r++) {
        float mnew = fmaxf(m_run[r], mtv[r]);
        float al = exp2f(m_run[r] - mnew);
        l_run[r] *= al;
        m_run[r] = mnew;
#pragma unroll
        for (int dj = 0; dj < 16; dj++) o[dj][r] *= al;
      }
    }
#pragma unroll
    for (int r = 0; r < 4; r++) {
      float p0 = exp2f(s[0][r] - m_run[r]);
      float p1 = exp2f(s[1][r] - m_run[r]);
      l_run[r] += p0 + p1;  // per-lane partial over lr columns
      sP[(lg * 4 + r) * 40 + lr] = (__bf16)p0;
      sP[(lg * 4 + r) * 40 + 16 + lr] = (__bf16)p1;
    }
    bf16x8 pa = *(const bf16x8*)(sP + lr * 40 + lg * 8);

    // O += P * V  (V from paired-row swizzled sV[cur]; d-range [d0, d0+256))
#pragma unroll
    for (int dj = 0; dj < 16; dj++) {
      int d = dj * 16 + lr;
      int rr = d >> 1;
      int cp = (((d & 1) << 2) | lg) ^ (rr & 7);
      bf16x8 vf = *(const bf16x8*)(sV[cur] + rr * 64 + (cp << 3));
      o[dj] = __builtin_amdgcn_mfma_f32_16x16x32_bf16(pa, vf, o[dj], 0, 0, 0);
    }
  }

  // reduce per-lane l partials across the 16 lr lanes
#pragma unroll
  for (int r = 0; r < 4; r++) {
#pragma unroll
    for (int msk = 1; msk <= 8; msk <<= 1) l_run[r] += __shfl_xor(l_run[r], msk);
  }
  float inv[4];
#pragma unroll
  for (int r = 0; r < 4; r++) inv[r] = 1.0f / l_run[r];

  float* orow = out + (size_t)(b * 2048 + q0 + w * 16 + lg * 4) * 512 + d0;
#pragma unroll
  for (int dj = 0; dj < 16; dj++)
#pragma unroll
    for (int r = 0; r < 4; r++)
      orow[(size_t)r * 512 + dj * 16 + lr] = o[dj][r] * inv[r];
}

extern "C" void kernel_launch(void* const* d_in, const int* in_sizes, int n_in,
                              void* d_out, int out_size, void* d_ws, size_t ws_size,
                              hipStream_t stream) {
  (void)in_sizes; (void)n_in; (void)out_size; (void)ws_size;
  const float* x = (const float*)d_in[0];
  const float* Wq = (const float*)d_in[1];
  const float* bq = (const float*)d_in[2];
  const float* Wk = (const float*)d_in[3];
  const float* bk = (const float*)d_in[4];
  const float* Wv = (const float*)d_in[5];
  const float* bv = (const float*)d_in[6];
  float* out = (float*)d_out;
  char* ws = (char*)d_ws;
  __bf16* xb = (__bf16*)(ws);
  __bf16* Qb = (__bf16*)(ws + 16777216);
  __bf16* Kb = (__bf16*)(ws + 33554432);
  __bf16* Vt = (__bf16*)(ws + 50331648);
  __bf16* Wt = (__bf16*)(ws + 67108864);

  k_xconv<<<4096, 256, 0, stream>>>(x, xb);
  k_wt<<<dim3(16, 16, 3), 256, 0, stream>>>(Wq, Wk, Wv, Wt);
  k_gemm<<<dim3(512, 3), 256, 0, stream>>>(xb, Wt, bq, bk, bv, Qb, Kb, Vt);
  k_fa<<<512, 256, 0, stream>>>(Qb, Kb, Vt, out);
}

// Round 7
// 241.033 us; speedup vs baseline: 2.7645x; 2.7645x over previous
//
#include <hip/hip_runtime.h>

// B=8, N=2048, D_IN=D_OUT=512. out fp32 [8,2048,512].
// ws layout (bytes): xb@0 (16M), Qb@16M, Kb@32M, Vt@48M, Wt@64M(+1.5M).

typedef __bf16 bf16x8 __attribute__((ext_vector_type(8)));
typedef float f32x4 __attribute__((ext_vector_type(4)));

#define AS1G __attribute__((address_space(1)))
#define AS3L __attribute__((address_space(3)))

__device__ __forceinline__ void gload16(const void* g, void* l) {
  __builtin_amdgcn_global_load_lds((const AS1G void*)g, (AS3L void*)l, 16, 0, 0);
}

// ---------------- x fp32 -> bf16 ----------------
__global__ __launch_bounds__(256) void k_xconv(const float* __restrict__ x, __bf16* __restrict__ xb) {
  size_t i = ((size_t)blockIdx.x * 256 + threadIdx.x) * 8;
  const float4* p = (const float4*)(x + i);
  float4 a = p[0], b = p[1];
  bf16x8 v;
  v[0] = (__bf16)a.x; v[1] = (__bf16)a.y; v[2] = (__bf16)a.z; v[3] = (__bf16)a.w;
  v[4] = (__bf16)b.x; v[5] = (__bf16)b.y; v[6] = (__bf16)b.z; v[7] = (__bf16)b.w;
  *(bf16x8*)(xb + i) = v;
}

// ---------------- W [d][e] fp32 -> Wt [z][e][d] bf16 ----------------
__global__ __launch_bounds__(256) void k_wt(const float* __restrict__ Wq, const float* __restrict__ Wk,
                                            const float* __restrict__ Wv, __bf16* __restrict__ Wt) {
  __shared__ float t[32][33];
  int z = blockIdx.z;
  const float* W = (z == 0) ? Wq : (z == 1 ? Wk : Wv);
  int r0 = blockIdx.y * 32, c0 = blockIdx.x * 32;
  int tr = threadIdx.x >> 5, tc = threadIdx.x & 31;
#pragma unroll
  for (int p = 0; p < 4; p++)
    t[tr + p * 8][tc] = W[(size_t)(r0 + tr + p * 8) * 512 + c0 + tc];
  __syncthreads();
#pragma unroll
  for (int p = 0; p < 4; p++)
    Wt[(size_t)z * 262144 + (size_t)(c0 + tr + p * 8) * 512 + r0 + tc] = (__bf16)t[tc][tr + p * 8];
}

// ---------------- fused QKV GEMM: C = xb * Wz^T + bias ----------------
// 128x128 tile, BK=64, 4 waves (2x2 of 64x64), 16x16x32 bf16 MFMA.
// z==0 -> Qb (pre-scaled for exp2 softmax), z==1 -> Kb, z==2 -> Vt (TRANSPOSED store).
__global__ __launch_bounds__(256) void k_gemm(const __bf16* __restrict__ xb, const __bf16* __restrict__ Wt,
                                              const float* __restrict__ bq, const float* __restrict__ bk,
                                              const float* __restrict__ bv,
                                              __bf16* __restrict__ Qb, __bf16* __restrict__ Kb,
                                              __bf16* __restrict__ Vt) {
  __shared__ __bf16 sA[128 * 64];
  __shared__ __bf16 sB[128 * 64];
  int z = blockIdx.y;
  int bx = blockIdx.x;
  int m0 = (bx >> 2) * 128, e0 = (bx & 3) * 128;
  int tid = threadIdx.x, w = tid >> 6, l = tid & 63;
  int lr = l & 15, lg = l >> 4;
  int wm = (w & 1) * 64, wn = (w >> 1) * 64;
  const float* bias = (z == 0) ? bq : (z == 1 ? bk : bv);
  const __bf16* Wz = Wt + (size_t)z * 262144;

  float bval[4];
#pragma unroll
  for (int fn = 0; fn < 4; fn++) bval[fn] = bias[e0 + wn + fn * 16 + lr];

  f32x4 zero4 = {0.f, 0.f, 0.f, 0.f};
  f32x4 acc[4][4];
#pragma unroll
  for (int fm = 0; fm < 4; fm++)
#pragma unroll
    for (int fn = 0; fn < 4; fn++) acc[fm][fn] = zero4;

#pragma unroll 1
  for (int kt = 0; kt < 8; kt++) {
#pragma unroll
    for (int ii = 0; ii < 4; ii++) {
      int rt = (w * 4 + ii) * 8 + (l >> 3);
      int sw = ((l & 7) ^ (l >> 3)) << 3;
      gload16(xb + (size_t)(m0 + rt) * 512 + kt * 64 + sw, sA + (w * 4 + ii) * 512);
      gload16(Wz + (size_t)(e0 + rt) * 512 + kt * 64 + sw, sB + (w * 4 + ii) * 512);
    }
    __syncthreads();
#pragma unroll
    for (int kc = 0; kc < 2; kc++) {
      bf16x8 af[4], bfr[4];
#pragma unroll
      for (int f = 0; f < 4; f++) {
        int ra = wm + f * 16 + lr;
        af[f] = *(const bf16x8*)(sA + ra * 64 + (((kc * 4 + lg) ^ (ra & 7)) << 3));
        int rb = wn + f * 16 + lr;
        bfr[f] = *(const bf16x8*)(sB + rb * 64 + (((kc * 4 + lg) ^ (rb & 7)) << 3));
      }
#pragma unroll
      for (int fm = 0; fm < 4; fm++)
#pragma unroll
        for (int fn = 0; fn < 4; fn++)
          acc[fm][fn] = __builtin_amdgcn_mfma_f32_16x16x32_bf16(af[fm], bfr[fn], acc[fm][fn], 0, 0, 0);
    }
    __syncthreads();
  }

  if (z == 2) {
    // V transposed: Vt[b][e][n]; 4 consecutive n per lane -> 8B store.
    int bb = m0 >> 11;
#pragma unroll
    for (int fm = 0; fm < 4; fm++) {
      int nl = (m0 & 2047) + wm + fm * 16 + lg * 4;
#pragma unroll
      for (int fn = 0; fn < 4; fn++) {
        alignas(8) __bf16 tmp[4];
#pragma unroll
        for (int r = 0; r < 4; r++) tmp[r] = (__bf16)(acc[fm][fn][r] + bval[fn]);
        *(float2*)(Vt + (size_t)bb * 1048576 + (size_t)(e0 + wn + fn * 16 + lr) * 2048 + nl) =
            *(float2*)tmp;
      }
    }
  } else {
    __bf16* dst = (z == 0) ? Qb : Kb;
    const float qmul = (z == 0) ? (1.4426950408889634f * 0.044194173824159216f) : 1.0f;
#pragma unroll
    for (int fm = 0; fm < 4; fm++)
#pragma unroll
      for (int fn = 0; fn < 4; fn++)
#pragma unroll
        for (int r = 0; r < 4; r++) {
          float v = (acc[fm][fn][r] + bval[fn]) * qmul;
          dst[(size_t)(m0 + wm + fm * 16 + lg * 4 + r) * 512 + e0 + wn + fn * 16 + lr] = (__bf16)v;
        }
  }
}

// ---------------- flash attention, D-split block pairs (round-4 structure) ----------
// grid 512: b = blk&7 (XCD pin), qt = (blk>>3)&31, dh = blk>>8 (output D-half).
// 256 threads = 4 waves x 16 q-rows. KVBLK=32. Full QK^T + softmax per block
// (duplicated across the dh pair); PV/output only for 256 d-cols.
// Round-7 deltas vs round-4:
//  * sV layout [256 d][32 kv], 64B rows, linear — PROVABLY bank-uniform for both
//    the gload16 write and the PV b128 read. Round-4's paired-row layout put
//    16 lanes on each 4-bank group during PV (2x serialization) = the 1.73e7
//    conflict cycles (~15% of CU-cycles).
//  * s_setprio(1) around both MFMA clusters (T5; 2 blocks/CU = phase-diverse waves).
// NOTE: 512-thread blocks pin VGPR to 128 -> spills (rounds 2-3). 256 threads OK.
__global__ __launch_bounds__(256, 2) void k_fa(const __bf16* __restrict__ Qb, const __bf16* __restrict__ Kb,
                                               const __bf16* __restrict__ Vt, float* __restrict__ out) {
  __shared__ __bf16 sK[32 * 512];   // [32 kv][512 d], XOR-8 16B-chunk swizzle per row
  __shared__ __bf16 sV[256 * 32];   // [d - d0][32 kv], 64B rows, linear (conflict-free)
  __shared__ __bf16 sPall[4 * 640]; // per-wave [16][40]

  int tid = threadIdx.x;
  int w = tid >> 6, l = tid & 63;
  int lr = l & 15, lg = l >> 4;
  __bf16* sP = sPall + w * 640;

  int blk = blockIdx.x;
  int b = blk & 7;
  int q0 = ((blk >> 3) & 31) * 64;
  int d0 = (blk >> 8) * 256;

  const __bf16* Kbase = Kb + (size_t)b * 2048 * 512;
  const __bf16* Vbase = Vt + (size_t)b * 512 * 2048 + (size_t)d0 * 2048;

  // Q A-fragments in registers, full 512 dims (already scaled by log2e/sqrt(512)).
  bf16x8 qf[16];
  const __bf16* qrow = Qb + (size_t)(b * 2048 + q0 + w * 16 + lr) * 512;
#pragma unroll
  for (int dk = 0; dk < 16; dk++) qf[dk] = *(const bf16x8*)(qrow + dk * 32 + lg * 8);

  f32x4 zero4 = {0.f, 0.f, 0.f, 0.f};
  f32x4 o[16];
#pragma unroll
  for (int dj = 0; dj < 16; dj++) o[dj] = zero4;
  float m_run[4] = {-1e30f, -1e30f, -1e30f, -1e30f};
  float l_run[4] = {0.f, 0.f, 0.f, 0.f};

  // prologue: stage K(0) — 8 rows per wave, 1KB row per instr
#pragma unroll
  for (int i = 0; i < 8; i++) {
    int row = w * 8 + i;
    gload16(Kbase + (size_t)row * 512 + ((l ^ i) << 3), sK + row * 512);
  }

#pragma unroll 1
  for (int it = 0; it < 64; it++) {
    int kv0 = it * 32;
    __syncthreads();  // B1: K(it) landed; PV(it-1) sV reads done

    // stage V(it): 4 instrs/wave, each fills 16 rows (1KB). Linear dest; lane
    // lam covers (row = R0 + lam/4, kv-chunk = (lam&3)*8) — coalesced 128B/row src.
#pragma unroll
    for (int i = 0; i < 4; i++) {
      int R0 = (w * 4 + i) * 16;
      int row = R0 + (l >> 2);
      gload16(Vbase + (size_t)row * 2048 + kv0 + ((l & 3) << 3), sV + R0 * 32);
    }

    // S = Q K^T (exp2 domain, scale folded into Q)
    f32x4 s[2] = {zero4, zero4};
    __builtin_amdgcn_s_setprio(1);
#pragma unroll
    for (int dk = 0; dk < 16; dk++) {
#pragma unroll
      for (int j = 0; j < 2; j++) {
        int row = j * 16 + lr;
        bf16x8 kf = *(const bf16x8*)(sK + row * 512 + (((dk * 4 + lg) ^ (row & 7)) << 3));
        s[j] = __builtin_amdgcn_mfma_f32_16x16x32_bf16(qf[dk], kf, s[j], 0, 0, 0);
      }
    }
    __builtin_amdgcn_s_setprio(0);
    __syncthreads();  // B2: V(it) landed; all sK(it) reads done

    // stage K(it+1) — overlaps softmax+PV
    if (it < 63) {
#pragma unroll
      for (int i = 0; i < 8; i++) {
        int row = w * 8 + i;
        gload16(Kbase + (size_t)(kv0 + 32 + row) * 512 + ((l ^ i) << 3), sK + row * 512);
      }
    }

    // online softmax with defer-rescale (THR=10 in log2 domain)
    float mtv[4];
#pragma unroll
    for (int r = 0; r < 4; r++) {
      float mt = fmaxf(s[0][r], s[1][r]);
#pragma unroll
      for (int msk = 1; msk <= 8; msk <<= 1) mt = fmaxf(mt, __shfl_xor(mt, msk));
      mtv[r] = mt;
    }
    float g4 = fmaxf(fmaxf(mtv[0] - m_run[0], mtv[1] - m_run[1]),
                     fmaxf(mtv[2] - m_run[2], mtv[3] - m_run[3]));
    if (__any(g4 > 10.0f)) {
#pragma unroll
      for (int r = 0; r < 4; r++) {
        float mnew = fmaxf(m_run[r], mtv[r]);
        float al = exp2f(m_run[r] - mnew);
        l_run[r] *= al;
        m_run[r] = mnew;
#pragma unroll
        for (int dj = 0; dj < 16; dj++) o[dj][r] *= al;
      }
    }
#pragma unroll
    for (int r = 0; r < 4; r++) {
      float p0 = exp2f(s[0][r] - m_run[r]);
      float p1 = exp2f(s[1][r] - m_run[r]);
      l_run[r] += p0 + p1;  // per-lane partial over lr columns
      sP[(lg * 4 + r) * 40 + lr] = (__bf16)p0;
      sP[(lg * 4 + r) * 40 + 16 + lr] = (__bf16)p1;
    }
    bf16x8 pa = *(const bf16x8*)(sP + lr * 40 + lg * 8);

    // O += P * V   (B-frag: lane (lr,lg) needs V[kv = lg*8..+7][d = dj*16+lr])
    __builtin_amdgcn_s_setprio(1);
#pragma unroll
    for (int dj = 0; dj < 16; dj++) {
      int d = dj * 16 + lr;
      bf16x8 vf = *(const bf16x8*)(sV + d * 32 + lg * 8);
      o[dj] = __builtin_amdgcn_mfma_f32_16x16x32_bf16(pa, vf, o[dj], 0, 0, 0);
    }
    __builtin_amdgcn_s_setprio(0);
  }

  // reduce per-lane l partials across the 16 lr lanes
#pragma unroll
  for (int r = 0; r < 4; r++) {
#pragma unroll
    for (int msk = 1; msk <= 8; msk <<= 1) l_run[r] += __shfl_xor(l_run[r], msk);
  }
  float inv[4];
#pragma unroll
  for (int r = 0; r < 4; r++) inv[r] = 1.0f / l_run[r];

  float* orow = out + (size_t)(b * 2048 + q0 + w * 16 + lg * 4) * 512 + d0;
#pragma unroll
  for (int dj = 0; dj < 16; dj++)
#pragma unroll
    for (int r = 0; r < 4; r++)
      orow[(size_t)r * 512 + dj * 16 + lr] = o[dj][r] * inv[r];
}

extern "C" void kernel_launch(void* const* d_in, const int* in_sizes, int n_in,
                              void* d_out, int out_size, void* d_ws, size_t ws_size,
                              hipStream_t stream) {
  (void)in_sizes; (void)n_in; (void)out_size; (void)ws_size;
  const float* x = (const float*)d_in[0];
  const float* Wq = (const float*)d_in[1];
  const float* bq = (const float*)d_in[2];
  const float* Wk = (const float*)d_in[3];
  const float* bk = (const float*)d_in[4];
  const float* Wv = (const float*)d_in[5];
  const float* bv = (const float*)d_in[6];
  float* out = (float*)d_out;
  char* ws = (char*)d_ws;
  __bf16* xb = (__bf16*)(ws);
  __bf16* Qb = (__bf16*)(ws + 16777216);
  __bf16* Kb = (__bf16*)(ws + 33554432);
  __bf16* Vt = (__bf16*)(ws + 50331648);
  __bf16* Wt = (__bf16*)(ws + 67108864);

  k_xconv<<<4096, 256, 0, stream>>>(x, xb);
  k_wt<<<dim3(16, 16, 3), 256, 0, stream>>>(Wq, Wk, Wv, Wt);
  k_gemm<<<dim3(512, 3), 256, 0, stream>>>(xb, Wt, bq, bk, bv, Qb, Kb, Vt);
  k_fa<<<512, 256, 0, stream>>>(Qb, Kb, Vt, out);
}

// Round 9
// 217.347 us; speedup vs baseline: 3.0657x; 1.1090x over previous
//
#include <hip/hip_runtime.h>

// B=8, N=2048, D_IN=D_OUT=512. out fp32 [8,2048,512].
// ws layout (bytes): xb@0 (16M), Qb@16M, Kb@32M, Vt@48M, Wt@64M(+1.5M).

typedef __bf16 bf16x8 __attribute__((ext_vector_type(8)));
typedef float f32x4 __attribute__((ext_vector_type(4)));

#define AS1G __attribute__((address_space(1)))
#define AS3L __attribute__((address_space(3)))

__device__ __forceinline__ void gload16(const void* g, void* l) {
  __builtin_amdgcn_global_load_lds((const AS1G void*)g, (AS3L void*)l, 16, 0, 0);
}

// ---------------- x fp32 -> bf16 ----------------
__global__ __launch_bounds__(256) void k_xconv(const float* __restrict__ x, __bf16* __restrict__ xb) {
  size_t i = ((size_t)blockIdx.x * 256 + threadIdx.x) * 8;
  const float4* p = (const float4*)(x + i);
  float4 a = p[0], b = p[1];
  bf16x8 v;
  v[0] = (__bf16)a.x; v[1] = (__bf16)a.y; v[2] = (__bf16)a.z; v[3] = (__bf16)a.w;
  v[4] = (__bf16)b.x; v[5] = (__bf16)b.y; v[6] = (__bf16)b.z; v[7] = (__bf16)b.w;
  *(bf16x8*)(xb + i) = v;
}

// ---------------- W [d][e] fp32 -> Wt [z][e][d] bf16 ----------------
__global__ __launch_bounds__(256) void k_wt(const float* __restrict__ Wq, const float* __restrict__ Wk,
                                            const float* __restrict__ Wv, __bf16* __restrict__ Wt) {
  __shared__ float t[32][33];
  int z = blockIdx.z;
  const float* W = (z == 0) ? Wq : (z == 1 ? Wk : Wv);
  int r0 = blockIdx.y * 32, c0 = blockIdx.x * 32;
  int tr = threadIdx.x >> 5, tc = threadIdx.x & 31;
#pragma unroll
  for (int p = 0; p < 4; p++)
    t[tr + p * 8][tc] = W[(size_t)(r0 + tr + p * 8) * 512 + c0 + tc];
  __syncthreads();
#pragma unroll
  for (int p = 0; p < 4; p++)
    Wt[(size_t)z * 262144 + (size_t)(c0 + tr + p * 8) * 512 + r0 + tc] = (__bf16)t[tc][tr + p * 8];
}

// ---------------- fused QKV GEMM: C = xb * Wz^T + bias ----------------
// 128x128 tile, BK=64, 4 waves (2x2 of 64x64), 16x16x32 bf16 MFMA.
// z==0 -> Qb (pre-scaled for exp2 softmax), z==1 -> Kb, z==2 -> Vt (TRANSPOSED store).
__global__ __launch_bounds__(256) void k_gemm(const __bf16* __restrict__ xb, const __bf16* __restrict__ Wt,
                                              const float* __restrict__ bq, const float* __restrict__ bk,
                                              const float* __restrict__ bv,
                                              __bf16* __restrict__ Qb, __bf16* __restrict__ Kb,
                                              __bf16* __restrict__ Vt) {
  __shared__ __bf16 sA[128 * 64];
  __shared__ __bf16 sB[128 * 64];
  int z = blockIdx.y;
  int bx = blockIdx.x;
  int m0 = (bx >> 2) * 128, e0 = (bx & 3) * 128;
  int tid = threadIdx.x, w = tid >> 6, l = tid & 63;
  int lr = l & 15, lg = l >> 4;
  int wm = (w & 1) * 64, wn = (w >> 1) * 64;
  const float* bias = (z == 0) ? bq : (z == 1 ? bk : bv);
  const __bf16* Wz = Wt + (size_t)z * 262144;

  float bval[4];
#pragma unroll
  for (int fn = 0; fn < 4; fn++) bval[fn] = bias[e0 + wn + fn * 16 + lr];

  f32x4 zero4 = {0.f, 0.f, 0.f, 0.f};
  f32x4 acc[4][4];
#pragma unroll
  for (int fm = 0; fm < 4; fm++)
#pragma unroll
    for (int fn = 0; fn < 4; fn++) acc[fm][fn] = zero4;

#pragma unroll 1
  for (int kt = 0; kt < 8; kt++) {
#pragma unroll
    for (int ii = 0; ii < 4; ii++) {
      int rt = (w * 4 + ii) * 8 + (l >> 3);
      int sw = ((l & 7) ^ (l >> 3)) << 3;
      gload16(xb + (size_t)(m0 + rt) * 512 + kt * 64 + sw, sA + (w * 4 + ii) * 512);
      gload16(Wz + (size_t)(e0 + rt) * 512 + kt * 64 + sw, sB + (w * 4 + ii) * 512);
    }
    __syncthreads();
#pragma unroll
    for (int kc = 0; kc < 2; kc++) {
      bf16x8 af[4], bfr[4];
#pragma unroll
      for (int f = 0; f < 4; f++) {
        int ra = wm + f * 16 + lr;
        af[f] = *(const bf16x8*)(sA + ra * 64 + (((kc * 4 + lg) ^ (ra & 7)) << 3));
        int rb = wn + f * 16 + lr;
        bfr[f] = *(const bf16x8*)(sB + rb * 64 + (((kc * 4 + lg) ^ (rb & 7)) << 3));
      }
#pragma unroll
      for (int fm = 0; fm < 4; fm++)
#pragma unroll
        for (int fn = 0; fn < 4; fn++)
          acc[fm][fn] = __builtin_amdgcn_mfma_f32_16x16x32_bf16(af[fm], bfr[fn], acc[fm][fn], 0, 0, 0);
    }
    __syncthreads();
  }

  if (z == 2) {
    // V transposed: Vt[b][e][n]; 4 consecutive n per lane -> 8B store.
    int bb = m0 >> 11;
#pragma unroll
    for (int fm = 0; fm < 4; fm++) {
      int nl = (m0 & 2047) + wm + fm * 16 + lg * 4;
#pragma unroll
      for (int fn = 0; fn < 4; fn++) {
        alignas(8) __bf16 tmp[4];
#pragma unroll
        for (int r = 0; r < 4; r++) tmp[r] = (__bf16)(acc[fm][fn][r] + bval[fn]);
        *(float2*)(Vt + (size_t)bb * 1048576 + (size_t)(e0 + wn + fn * 16 + lr) * 2048 + nl) =
            *(float2*)tmp;
      }
    }
  } else {
    __bf16* dst = (z == 0) ? Qb : Kb;
    const float qmul = (z == 0) ? (1.4426950408889634f * 0.044194173824159216f) : 1.0f;
#pragma unroll
    for (int fm = 0; fm < 4; fm++)
#pragma unroll
      for (int fn = 0; fn < 4; fn++)
#pragma unroll
        for (int r = 0; r < 4; r++) {
          float v = (acc[fm][fn][r] + bval[fn]) * qmul;
          dst[(size_t)(m0 + wm + fm * 16 + lg * 4 + r) * 512 + e0 + wn + fn * 16 + lr] = (__bf16)v;
        }
  }
}

// ---------------- flash attention, swapped-QK + in-register P redistribution ----------
// grid 512: b = blk&7 (XCD pin), qt = (blk>>3)&31, dh = blk>>8 (output D-half).
// 256 threads = 4 waves x 16 q-rows. KVBLK=32. Full QK^T+softmax per block; PV for 256 d.
// Round-9 delta vs round-8: sK SKEW REMOVED. The (w&1)*8 skew made each gload16
// spill 16B past its 8-row group into the next wave's first chunk (round-8
// correctness failure, absmax 5.5e-2). sK write/read = exact round-4/7 pattern
// (re-derived conflict-free at 8-lane b128 issue granularity).
// Kept from round-8: swapped QK (s = mfma(K,Q) -> lane holds S[kv=lg*4+r+16j][q=lr]),
// softmax reduce = 2 shfl_xor, P->PV-A-frag redistribution fully in registers
// (sP LDS buffer eliminated — its bf16 scatter was ~4-way bank-aliased, the
// prime suspect for the 1.73e7 conflict cycles present in rounds 4 AND 7).
__global__ __launch_bounds__(256, 2) void k_fa(const __bf16* __restrict__ Qb, const __bf16* __restrict__ Kb,
                                               const __bf16* __restrict__ Vt, float* __restrict__ out) {
  __shared__ __bf16 sK[32 * 512];  // [32 kv][512 d], XOR-8 16B-chunk swizzle per row
  __shared__ __bf16 sV[128 * 64];  // paired d-rows: rr=(d-d0)>>1, XOR-swz chunks (round-4 layout)

  int tid = threadIdx.x;
  int w = tid >> 6, l = tid & 63;
  int lr = l & 15, lg = l >> 4;

  int blk = blockIdx.x;
  int b = blk & 7;
  int q0 = ((blk >> 3) & 31) * 64;
  int d0 = (blk >> 8) * 256;

  const __bf16* Kbase = Kb + (size_t)b * 2048 * 512;
  const __bf16* Vbase = Vt + (size_t)b * 512 * 2048 + (size_t)d0 * 2048;

  // Q B-fragments in registers, full 512 dims (already scaled by log2e/sqrt(512)).
  bf16x8 qf[16];
  const __bf16* qrow = Qb + (size_t)(b * 2048 + q0 + w * 16 + lr) * 512;
#pragma unroll
  for (int dk = 0; dk < 16; dk++) qf[dk] = *(const bf16x8*)(qrow + dk * 32 + lg * 8);

  f32x4 zero4 = {0.f, 0.f, 0.f, 0.f};
  f32x4 o[16];
#pragma unroll
  for (int dj = 0; dj < 16; dj++) o[dj] = zero4;
  float m_run = -1e30f;  // per-lane, q = lr
  float l_run = 0.f;     // per-lane partial (own 8 kv cols per iter)

  // prologue: stage K(0) — 8 rows per wave, 1KB row per instr
#pragma unroll
  for (int i = 0; i < 8; i++) {
    int row = w * 8 + i;
    gload16(Kbase + (size_t)row * 512 + ((l ^ i) << 3), sK + row * 512);
  }

#pragma unroll 1
  for (int it = 0; it < 64; it++) {
    int kv0 = it * 32;
    __syncthreads();  // B1: K(it) landed; PV(it-1) sV reads done

    // stage V(it) — round-4 paired-row pattern, overlaps QK
#pragma unroll
    for (int i = 0; i < 4; i++) {
      int rr = (w * 4 + i) * 8 + (l >> 3);
      int cl = (l & 7) ^ (l >> 3);
      gload16(Vbase + (size_t)(2 * rr + (cl >> 2)) * 2048 + kv0 + ((cl & 3) << 3),
              sV + (w * 4 + i) * 512);
    }

    // S^T = K Q^T (swapped): lane (lr,lg) holds S[kv=lg*4+r+16j][q=lr]
    f32x4 s[2] = {zero4, zero4};
    __builtin_amdgcn_s_setprio(1);
#pragma unroll
    for (int dk = 0; dk < 16; dk++) {
#pragma unroll
      for (int j = 0; j < 2; j++) {
        int row = j * 16 + lr;
        bf16x8 kf = *(const bf16x8*)(sK + row * 512 + (((dk * 4 + lg) ^ (lr & 7)) << 3));
        s[j] = __builtin_amdgcn_mfma_f32_16x16x32_bf16(kf, qf[dk], s[j], 0, 0, 0);
      }
    }
    __builtin_amdgcn_s_setprio(0);
    __syncthreads();  // B2: V(it) landed; all sK(it) reads done

    // stage K(it+1) — overlaps softmax+PV
    if (it < 63) {
#pragma unroll
      for (int i = 0; i < 8; i++) {
        int row = w * 8 + i;
        gload16(Kbase + (size_t)(kv0 + 32 + row) * 512 + ((l ^ i) << 3), sK + row * 512);
      }
    }

    // online softmax (per-lane q=lr), defer-rescale THR=10 (log2 domain)
    float mt = fmaxf(fmaxf(fmaxf(s[0][0], s[0][1]), fmaxf(s[0][2], s[0][3])),
                     fmaxf(fmaxf(s[1][0], s[1][1]), fmaxf(s[1][2], s[1][3])));
    mt = fmaxf(mt, __shfl_xor(mt, 16));
    mt = fmaxf(mt, __shfl_xor(mt, 32));
    if (__any(mt - m_run > 10.0f)) {
      float mnew = fmaxf(m_run, mt);
      float al = exp2f(m_run - mnew);
      // o[] rows are q = lg*4+r; alpha lives at lane q (lg'=0 copy)
      float a0 = __shfl(al, lg * 4 + 0);
      float a1 = __shfl(al, lg * 4 + 1);
      float a2 = __shfl(al, lg * 4 + 2);
      float a3 = __shfl(al, lg * 4 + 3);
      l_run *= al;
      m_run = mnew;
#pragma unroll
      for (int dj = 0; dj < 16; dj++) {
        o[dj][0] *= a0; o[dj][1] *= a1; o[dj][2] *= a2; o[dj][3] *= a3;
      }
    }
    float p00 = exp2f(s[0][0] - m_run), p01 = exp2f(s[0][1] - m_run);
    float p02 = exp2f(s[0][2] - m_run), p03 = exp2f(s[0][3] - m_run);
    float p10 = exp2f(s[1][0] - m_run), p11 = exp2f(s[1][1] - m_run);
    float p12 = exp2f(s[1][2] - m_run), p13 = exp2f(s[1][3] - m_run);
    l_run += ((p00 + p01) + (p02 + p03)) + ((p10 + p11) + (p12 + p13));

    // pack P to bf16 pairs and redistribute to PV A-fragment (q=lr, kv=lg*8..+7)
    union Pk { unsigned u; __bf16 h[2]; };
    Pk A0, A1, B0, B1;
    A0.h[0] = (__bf16)p00; A0.h[1] = (__bf16)p01;  // kv (lg*4, lg*4+1)
    A1.h[0] = (__bf16)p02; A1.h[1] = (__bf16)p03;  // kv (lg*4+2, +3)
    B0.h[0] = (__bf16)p10; B0.h[1] = (__bf16)p11;  // kv (16+lg*4, +1)
    B1.h[0] = (__bf16)p12; B1.h[1] = (__bf16)p13;  // kv (16+lg*4+2, +3)
    unsigned a0s = __shfl_xor(A0.u, 16), a1s = __shfl_xor(A1.u, 16);
    unsigned b0s = __shfl_xor(B0.u, 16), b1s = __shfl_xor(B1.u, 16);
    bool lo = (lg & 1) != 0, hi = (lg & 2) != 0;
    // FA = this pair's kv-octet of j=0 (pair0: kv0-7, pair1: kv8-15); FB = j=1 octet
    unsigned FA0 = lo ? a0s : A0.u, FA1 = lo ? a1s : A1.u;
    unsigned FA2 = lo ? A0.u : a0s, FA3 = lo ? A1.u : a1s;
    unsigned FB0 = lo ? b0s : B0.u, FB1 = lo ? b1s : B1.u;
    unsigned FB2 = lo ? B0.u : b0s, FB3 = lo ? B1.u : b1s;
    // cross-pair exchange: pair1 sends FA (to lg1), pair0 sends FB (to lg2)
    unsigned R0 = __shfl_xor(hi ? FA0 : FB0, 32);
    unsigned R1 = __shfl_xor(hi ? FA1 : FB1, 32);
    unsigned R2 = __shfl_xor(hi ? FA2 : FB2, 32);
    unsigned R3 = __shfl_xor(hi ? FA3 : FB3, 32);
    bool mid = lo != hi;  // lg==1 || lg==2 take the received octet
    union Fr { unsigned u[4]; bf16x8 v; } pa_u;
    pa_u.u[0] = mid ? R0 : (hi ? FB0 : FA0);
    pa_u.u[1] = mid ? R1 : (hi ? FB1 : FA1);
    pa_u.u[2] = mid ? R2 : (hi ? FB2 : FA2);
    pa_u.u[3] = mid ? R3 : (hi ? FB3 : FA3);
    bf16x8 pa = pa_u.v;

    // O += P * V  (V from paired-row swizzled sV, round-4 pattern)
    __builtin_amdgcn_s_setprio(1);
#pragma unroll
    for (int dj = 0; dj < 16; dj++) {
      int d = dj * 16 + lr;
      int rr = d >> 1;
      int cp = (((d & 1) << 2) | lg) ^ (rr & 7);
      bf16x8 vf = *(const bf16x8*)(sV + rr * 64 + (cp << 3));
      o[dj] = __builtin_amdgcn_mfma_f32_16x16x32_bf16(pa, vf, o[dj], 0, 0, 0);
    }
    __builtin_amdgcn_s_setprio(0);
  }

  // finish l: reduce across the 4 lanes of each q-group, then gather to o-layout
  l_run += __shfl_xor(l_run, 16);
  l_run += __shfl_xor(l_run, 32);
  float i0 = 1.0f / __shfl(l_run, lg * 4 + 0);
  float i1 = 1.0f / __shfl(l_run, lg * 4 + 1);
  float i2 = 1.0f / __shfl(l_run, lg * 4 + 2);
  float i3 = 1.0f / __shfl(l_run, lg * 4 + 3);

  float* orow = out + (size_t)(b * 2048 + q0 + w * 16 + lg * 4) * 512 + d0;
#pragma unroll
  for (int dj = 0; dj < 16; dj++) {
    orow[(size_t)0 * 512 + dj * 16 + lr] = o[dj][0] * i0;
    orow[(size_t)1 * 512 + dj * 16 + lr] = o[dj][1] * i1;
    orow[(size_t)2 * 512 + dj * 16 + lr] = o[dj][2] * i2;
    orow[(size_t)3 * 512 + dj * 16 + lr] = o[dj][3] * i3;
  }
}

extern "C" void kernel_launch(void* const* d_in, const int* in_sizes, int n_in,
                              void* d_out, int out_size, void* d_ws, size_t ws_size,
                              hipStream_t stream) {
  (void)in_sizes; (void)n_in; (void)out_size; (void)ws_size;
  const float* x = (const float*)d_in[0];
  const float* Wq = (const float*)d_in[1];
  const float* bq = (const float*)d_in[2];
  const float* Wk = (const float*)d_in[3];
  const float* bk = (const float*)d_in[4];
  const float* Wv = (const float*)d_in[5];
  const float* bv = (const float*)d_in[6];
  float* out = (float*)d_out;
  char* ws = (char*)d_ws;
  __bf16* xb = (__bf16*)(ws);
  __bf16* Qb = (__bf16*)(ws + 16777216);
  __bf16* Kb = (__bf16*)(ws + 33554432);
  __bf16* Vt = (__bf16*)(ws + 50331648);
  __bf16* Wt = (__bf16*)(ws + 67108864);

  k_xconv<<<4096, 256, 0, stream>>>(x, xb);
  k_wt<<<dim3(16, 16, 3), 256, 0, stream>>>(Wq, Wk, Wv, Wt);
  k_gemm<<<dim3(512, 3), 256, 0, stream>>>(xb, Wt, bq, bk, bv, Qb, Kb, Vt);
  k_fa<<<512, 256, 0, stream>>>(Qb, Kb, Vt, out);
}